// Round 16
// baseline (1818.976 us; speedup 1.0000x reference)
//
#include <hip/hip_runtime.h>
#include <hip/hip_fp16.h>
#include <stdint.h>

// ---------- types ----------
typedef _Float16 half8 __attribute__((ext_vector_type(8)));
typedef _Float16 h2v __attribute__((ext_vector_type(2)));
typedef float f32x16 __attribute__((ext_vector_type(16)));

#define GLD_LDS16(gp, lp)                                                     \
  __builtin_amdgcn_global_load_lds(                                           \
      (const __attribute__((address_space(1))) void*)(gp),                    \
      (__attribute__((address_space(3))) void*)(lp), 16, 0, 0)
#define GLD_LDS4(gp, lp)                                                      \
  __builtin_amdgcn_global_load_lds(                                           \
      (const __attribute__((address_space(1))) void*)(gp),                    \
      (__attribute__((address_space(3))) void*)(lp), 4, 0, 0)

// ---------- x convert: fp32 (harness upcast) -> fp16 ----------
__global__ void xcvt_kernel(const float* __restrict__ in, __half* __restrict__ out) {
  const size_t i = ((size_t)blockIdx.x * 256 + threadIdx.x) * 4;
  float4 v = *(const float4*)(in + i);
  __half2* o = (__half2*)(out + i);
  o[0] = __floats2half2_rn(v.x, v.y);
  o[1] = __floats2half2_rn(v.z, v.w);
}

// ---------- repack: qweight [K][N/8] col-packed -> [K/8][N] k-packed ----------
// Output dword for (q, n): nibble of k=8q+t at bits 4*(t>>1)+16*(t&1).
__global__ void repack_kernel(const int* __restrict__ qw, uint32_t* __restrict__ rp, int P) {
  const int N = P * 8;
  const int n = blockIdx.x * 256 + threadIdx.x;
  const int j8 = n >> 3;
  const int sh = (n & 7) * 4;
  #pragma unroll
  for (int qi = 0; qi < 4; ++qi) {
    const int q = blockIdx.y * 4 + qi;
    const int* src = qw + (size_t)(q * 8) * P + j8;
    uint32_t r = 0;
    #pragma unroll
    for (int t = 0; t < 8; ++t) {
      uint32_t w = ((uint32_t)src[t * P] >> sh) & 15u;
      r |= w << (4 * (t >> 1) + 16 * (t & 1));
    }
    rp[(size_t)q * N + n] = r;
  }
}

// ---------- smz: per (group, col) pack (s_bits, (1024+z)_bits) ----------
__global__ void smz_kernel(const float* __restrict__ sc, const int* __restrict__ qz,
                           uint32_t* __restrict__ smz, int P) {
  const int N = P * 8;
  const int n = blockIdx.x * 256 + threadIdx.x;
  const int g = blockIdx.y;
  uint32_t sbits = __half_as_ushort(__float2half(sc[(size_t)g * N + n]));  // exact
  uint32_t z = ((uint32_t)qz[(size_t)g * P + (n >> 3)] >> ((n & 7) * 4)) & 15u;
  uint32_t hz = 0x6400u | z;  // fp16(1024+z), exact
  smz[(size_t)g * N + n] = sbits | (hz << 16);
}

// ---------- dequant 8 nibbles -> half8 (pk-f16 ops) ----------
union U32H2 { uint32_t u; h2v h; };
__device__ inline h2v bith2(uint32_t u) { U32H2 t; t.u = u; return t.h; }
__device__ inline uint32_t h2bit(h2v h) { U32H2 t; t.h = h; return t.u; }
__device__ inline half8 dequant8(uint32_t p, h2v s, h2v z) {
  union { uint32_t u[4]; half8 v; } r;
  r.u[0] = h2bit((bith2((p & 0x000F000Fu) | 0x64006400u) - z) * s);
  r.u[1] = h2bit((bith2(((p >> 4) & 0x000F000Fu) | 0x64006400u) - z) * s);
  r.u[2] = h2bit((bith2(((p >> 8) & 0x000F000Fu) | 0x64006400u) - z) * s);
  r.u[3] = h2bit((bith2(((p >> 12) & 0x000F000Fu) | 0x64006400u) - z) * s);
  return r.v;  // v_pk_sub_f16 (exact) + v_pk_mul_f16 (1 rounding) per dword
}

// ====== fused AWQ GEMM: 32x32x16 MFMA, 4 waves/SIMD, R13 schedule ======
// Block: 512 threads = 8 waves. 128 rows x 256 LDS-cols (c<128 -> n0+c,
// c>=128 -> n0+T1OFF+(c-128); GEMM1: gate/up halves, GEMM2: contiguous).
// Wave wv owns ALL 128 rows x cols [wv*32, +32) of the 256-col space:
//   per K-step: 4 kf x {1 dequant8 -> 4 MFMA(32x32x16) over rf} = 16 MFMA,
//   acc = 4 x f32x16 = 64 VGPR -> launch_bounds(512,4): 4 waves/SIMD.
// 32x32 matrix pipe: 33.8 cyc/MFMA/SIMD (2382 TF) vs 16x16's 19.4 (2075)
// -> per wave-K-step matrix 541 vs 621 cyc at same FLOP/LDS/dequant counts.
// A: chunk-major [chunk8][row128]x16B (R11: conflict-free b128, 0 measured);
//    frag (kf,rf): addr = (kf*2+lh)*2048 + (rf*32+l31)*16.
// B: LINEAR [qr8][256 cols]x4B (R10: dword IS the lane fragment; 2-way free);
//    frag kf: dword[(kf*2+lh)*256 + wv*32+l31].
// C/D: col=l31, row = rf*32 + (reg&3)+8*(reg>>2)+4*lh  (R10/R11-verified).
// Schedule = R13 (proven): triple-buffer A+B, smz dbuf, ONE raw s_barrier
// per K-step preceded by COUNTED vmcnt; batch = 2A+1B (+1 smz if even) ->
// wait vmcnt(3) t even / vmcnt(4) t odd / vmcnt(0) last. LDS 75776 B ->
// 2 blocks/CU -> 16 waves/CU.
// SILU epilogue (GEMM1): waves 4-7 round up-acc to fp16 (required rounding
// point), write 32KB to the retired A-buffers, barrier; waves 0-3 read,
// apply silu(gate)*up, store interm.
template <int KDIM, int NW, int T1OFF, int OW, bool SILU, int BXS>
__global__ __launch_bounds__(512, 4) void awq_gemm(const __half* __restrict__ A,
                                                   const uint32_t* __restrict__ RP,
                                                   const uint32_t* __restrict__ SMZ,
                                                   void* __restrict__ OUT) {
  constexpr int ABUF = 8 * 128 * 16;          // 16384 B per A buffer (chunk-major)
  constexpr int BBUF = 8 * 256 * 4;           // 8192 B per B buffer
  constexpr int BOFF = 3 * ABUF;              // 49152
  constexpr int ZOFF = BOFF + 3 * BBUF;       // 73728; smz dbuf 2 x 1024
  __shared__ __align__(16) unsigned char smem[ZOFF + 2048];  // 75776

  const int tid = threadIdx.x;
  const int l = tid & 63;
  const int wv = tid >> 6;      // 0..7
  const int l31 = l & 31;
  const int lh = l >> 5;        // k-half selector

  const int row0 = blockIdx.y * 128;
  const int n0 = blockIdx.x * BXS;

  // A staging sources, chunk-major dest: iter it stages LDS[it*8192+tid*16]
  // = chunk (it*4 + tid>>7), row (tid&127).
  const __half* asrc[2];
  #pragma unroll
  for (int it = 0; it < 2; ++it)
    asrc[it] = A + (size_t)(row0 + (tid & 127)) * KDIM + (it * 4 + (tid >> 7)) * 8;

  // B staging source: dword (qr = tid>>6, c = (tid&63)*4..+3) = RP col map(c)
  const uint32_t* bsrc;
  {
    int qr = tid >> 6;
    int c4 = (tid & 63) * 4;
    int bcol = (c4 < 128) ? n0 + c4 : n0 + T1OFF + (c4 - 128);
    bsrc = RP + (size_t)qr * NW + bcol;
  }

  // SMZ staging source: zc = tid&255 covers 256 dwords (upper half duplicates)
  const uint32_t* zsrc;
  {
    int zc = tid & 255;
    zsrc = SMZ + ((zc < 128) ? n0 + zc : n0 + T1OFF + (zc - 128));
  }

  f32x16 acc[4];  // [rf]
  #pragma unroll
  for (int rf = 0; rf < 4; ++rf)
    #pragma unroll
    for (int e = 0; e < 16; ++e) acc[rf][e] = 0.f;

  uint32_t s2, z2;
  constexpr int NSTEP = KDIM / 64;

  // lane-constant offsets
  const int bidx = wv * 32 + l31;          // B/smz col index in 0..255
  const int arow16 = l31 * 16;             // + rf*512 + chunk*2048

  // ---- prologue: batch(0) [2A,1B,smz g0] then batch(1) [2A,1B] ----
  #pragma unroll
  for (int it = 0; it < 2; ++it)
    GLD_LDS16(asrc[it], &smem[it * 8192 + tid * 16]);
  GLD_LDS16(bsrc, &smem[BOFF + tid * 16]);
  GLD_LDS4(zsrc, &smem[ZOFF + (tid & 255) * 4]);
  #pragma unroll
  for (int it = 0; it < 2; ++it)
    GLD_LDS16(asrc[it] + 64, &smem[ABUF + it * 8192 + tid * 16]);
  GLD_LDS16(bsrc + (size_t)8 * NW, &smem[BOFF + BBUF + tid * 16]);

  int cur = 0, stg = 2;  // buf(t%3), buf((t+2)%3)
  for (int t = 0; t < NSTEP; ++t) {
    // counted wait: drain batch(t); batch(t+1) = 3 (+1 if t+1 even) in flight
    if (t == NSTEP - 1)      asm volatile("s_waitcnt vmcnt(0)" ::: "memory");
    else if (t & 1)          asm volatile("s_waitcnt vmcnt(4)" ::: "memory");
    else                     asm volatile("s_waitcnt vmcnt(3)" ::: "memory");
    __builtin_amdgcn_s_barrier();

    // issue batch(t+2) into buf stg
    if (t + 2 < NSTEP) {
      #pragma unroll
      for (int it = 0; it < 2; ++it)
        GLD_LDS16(asrc[it] + (size_t)(t + 2) * 64,
                  &smem[stg * ABUF + it * 8192 + tid * 16]);
      GLD_LDS16(bsrc + (size_t)(t + 2) * 8 * NW, &smem[BOFF + stg * BBUF + tid * 16]);
      if (((t + 2) & 1) == 0) {  // smz for group (t+2)/2 into zbuf (g&1)
        const int g = (t + 2) >> 1;
        GLD_LDS4(zsrc + (size_t)g * NW, &smem[ZOFF + (g & 1) * 1024 + (tid & 255) * 4]);
      }
    }

    if ((t & 1) == 0) {  // group boundary: unpack s/z from zbuf ((t>>1)&1)
      const uint32_t* zl = (const uint32_t*)&smem[ZOFF + ((t >> 1) & 1) * 1024];
      uint32_t u = zl[bidx];
      uint32_t lo = u & 0xFFFFu;
      s2 = lo | (lo << 16);
      z2 = (u & 0xFFFF0000u) | (u >> 16);
    }

    // B dwords: linear, (kf) -> qr = kf*2+lh
    uint32_t bq[4];
    const uint32_t* bdw = (const uint32_t*)&smem[BOFF + cur * BBUF];
    #pragma unroll
    for (int kf = 0; kf < 4; ++kf)
      bq[kf] = bdw[(kf * 2 + lh) * 256 + bidx];

    const unsigned char* abase = &smem[cur * ABUF];
    __builtin_amdgcn_s_setprio(1);
    #pragma unroll
    for (int kf = 0; kf < 4; ++kf) {
      half8 b = dequant8(bq[kf], bith2(s2), bith2(z2));
      const int coff = (kf * 2 + lh) * 2048 + arow16;
      #pragma unroll
      for (int rf = 0; rf < 4; ++rf) {
        half8 a = *(const half8*)(abase + coff + rf * 512);
        acc[rf] = __builtin_amdgcn_mfma_f32_32x32x16_f16(a, b, acc[rf], 0, 0, 0);
      }
    }
    __builtin_amdgcn_s_setprio(0);

    cur = (cur == 2) ? 0 : cur + 1;
    stg = (stg == 2) ? 0 : stg + 1;
  }

  // epilogue: C/D: col = l31, row = rf*32 + (reg&3) + 8*(reg>>2) + 4*lh
  if (SILU) {
    // cross-wave gate/up exchange through the retired A buffers (48KB >= 32KB)
    __half* uph = (__half*)smem;  // up[row][col] fp16, 128 x 128
    __syncthreads();              // all waves done reading A/B LDS
    if (wv >= 4) {
      const int col = (wv - 4) * 32 + l31;
      #pragma unroll
      for (int rf = 0; rf < 4; ++rf)
        #pragma unroll
        for (int reg = 0; reg < 16; ++reg) {
          int row = rf * 32 + (reg & 3) + 8 * (reg >> 2) + 4 * lh;
          uph[row * 128 + col] = __float2half(acc[rf][reg]);  // up fp16 cast
        }
    }
    __syncthreads();
    if (wv < 4) {
      __half* O = (__half*)OUT;
      const int col = wv * 32 + l31;
      #pragma unroll
      for (int rf = 0; rf < 4; ++rf)
        #pragma unroll
        for (int reg = 0; reg < 16; ++reg) {
          int row = rf * 32 + (reg & 3) + 8 * (reg >> 2) + 4 * lh;
          float gf = __half2float(__float2half(acc[rf][reg]));  // gate fp16 cast
          float uf = __half2float(uph[row * 128 + col]);
          float sig = 1.f / (1.f + __expf(-gf));
          float sil = __half2float(__float2half(gf * sig));     // silu fp16 cast
          O[(size_t)(row0 + row) * OW + n0 + col] = __float2half(sil * uf);
        }
    }
  } else {
    float* O = (float*)OUT;
    const int colc = bidx;  // 0..255 contiguous (T1OFF=128 keeps mapping linear)
    const int col = (colc < 128) ? n0 + colc : n0 + T1OFF + (colc - 128);
    #pragma unroll
    for (int rf = 0; rf < 4; ++rf)
      #pragma unroll
      for (int reg = 0; reg < 16; ++reg) {
        int row = rf * 32 + (reg & 3) + 8 * (reg >> 2) + 4 * lh;
        O[(size_t)(row0 + row) * OW + col] = __half2float(__float2half(acc[rf][reg]));
      }
  }
}

// ---------- launch ----------
// Workspace phase-aliasing (stay under round-1-proven-safe 263,397,376 B):
//   phase 1 (through GEMM1): interm | rp_gu | smz_gu | xh   = 256,688,128 B
//   phase 2 (after GEMM1):   interm | rp_dn | smz_dn        = 191,258,624 B
extern "C" void kernel_launch(void* const* d_in, const int* in_sizes, int n_in,
                              void* d_out, int out_size, void* d_ws, size_t ws_size,
                              hipStream_t stream) {
  const float* x_f32 = (const float*)d_in[0];          // harness upcasts fp16 -> fp32
  const int* qw_gu = (const int*)d_in[1];
  const int* qz_gu = (const int*)d_in[2];
  const float* sc_gu = (const float*)d_in[3];          // fp32 (upcast)
  const int* qw_dn = (const int*)d_in[4];
  const int* qz_dn = (const int*)d_in[5];
  const float* sc_dn = (const float*)d_in[6];          // fp32 (upcast)

  char* ws = (char*)d_ws;
  __half* interm   = (__half*)ws;                      // 155,189,248
  uint32_t* rp_gu  = (uint32_t*)(ws + 155189248ull);   // 67,895,296
  uint32_t* smz_gu = (uint32_t*)(ws + 223084544ull);   // 4,243,456
  __half* xh       = (__half*)(ws + 227328000ull);     // 29,360,128
  uint32_t* rp_dn  = (uint32_t*)(ws + 155189248ull);   // aliases rp_gu
  uint32_t* smz_dn = (uint32_t*)(ws + 189136896ull);

  // ---- phase 1: prep + GEMM1 ----
  xcvt_kernel<<<14336, 256, 0, stream>>>(x_f32, xh);
  repack_kernel<<<dim3(148, 112), 256, 0, stream>>>(qw_gu, rp_gu, 4736);
  smz_kernel<<<dim3(148, 28), 256, 0, stream>>>(sc_gu, qz_gu, smz_gu, 4736);

  // GEMM1: block = 128 rows x (128 gate at n0 + 128 up at n0+18944)
  awq_gemm<3584, 37888, 18944, 18944, true, 128>
      <<<dim3(148, 32), 512, 0, stream>>>(xh, rp_gu, smz_gu, (void*)interm);

  // ---- phase 2: prep + GEMM2 (aliased scratch) ----
  repack_kernel<<<dim3(14, 592), 256, 0, stream>>>(qw_dn, rp_dn, 448);
  smz_kernel<<<dim3(14, 148), 256, 0, stream>>>(sc_dn, qz_dn, smz_dn, 448);

  // GEMM2: block = 128 rows x 256 contiguous cols
  awq_gemm<18944, 3584, 128, 3584, false, 256>
      <<<dim3(14, 32), 512, 0, stream>>>(interm, rp_dn, smz_dn, d_out);
}